// Round 4
// baseline (662.037 us; speedup 1.0000x reference)
//
#include <hip/hip_runtime.h>
#include <hip/hip_bf16.h>

typedef unsigned short ushort_t;
typedef unsigned int uint_t;
typedef __attribute__((ext_vector_type(4))) float f32x4;
typedef __attribute__((ext_vector_type(8))) short bf16x8;

#define B_DIM 512
#define IN_DIM 4096
#define OUT_DIM 4096
#define BN 32
#define BK 32
#define KSPLIT 8

// ---------- helpers ----------
__device__ __forceinline__ ushort_t f2bf(float f) {
    union { float f; uint_t u; } v; v.f = f;
    uint_t r = v.u + 0x7fffu + ((v.u >> 16) & 1u);   // round-to-nearest-even
    return (ushort_t)(r >> 16);
}

// ---------- kernel 1: x -> bf16 ----------
__global__ __launch_bounds__(256) void conv_x(const float4* __restrict__ X4,
                                              ushort_t* __restrict__ Xb) {
    size_t i = (size_t)blockIdx.x * 256 + threadIdx.x;   // one float4 per thread
    float4 a = X4[i];
    ushort_t r[4] = { f2bf(a.x), f2bf(a.y), f2bf(a.z), f2bf(a.w) };
    *(uint2*)(Xb + i * 4) = *(const uint2*)r;            // 8B/lane coalesced
}

// ---------- kernel 2: barrier-free fused dequant-GEMM ----------
// Rounds 2-3 failed because __syncthreads drains vmcnt(0), exposing the full
// HBM latency of the U stream every K-step (prefetch cannot cross a barrier
// at HIP source level). Fix: NO LDS, NO barriers. The block's A tile had no
// intra-block reuse anyway (each element read once), so each lane loads its
// MFMA fragments directly: A frags 16B/lane from L2-resident Xb, U frags
// 8xfloat4/lane (HBM stream), dequant in registers. The 4 waves redundantly
// dequant the same 32x32 W tile (~6us VALU total, L1/L2-served) -- cheap vs
// the 43us U-stream floor. Manual 1-iter register prefetch of U now really
// carries across steps; compiler pipelines freely (no drains).
// Fragment mapping identical to the LDS-read mapping verified rounds 0-3.
__global__ __launch_bounds__(256, 2) void gemm_direct(
    const ushort_t* __restrict__ A,   // M x K bf16 (Xb)
    const float4* __restrict__ U4,    // (OUT*IN) float4 rows (p=0..3)
    const float* __restrict__ q,
    const int* __restrict__ expo,
    float* __restrict__ part)         // KSPLIT x M x N fp32
{
    const int M = B_DIM, N = OUT_DIM, K = IN_DIM;
    const int tid  = threadIdx.x;
    const int lane = tid & 63;
    const int wave = tid >> 6;

    const int n0 = blockIdx.x * BN;
    const int kseg = K / KSPLIT;                       // 512
    const size_t kbase = (size_t)blockIdx.y * kseg;

    const float scale = exp2f((float)expo[0]) * (1.0f / 7.0f);
    const float t0 = q[0] * scale, t1 = q[1] * scale,
                t2 = q[2] * scale, t3 = q[3] * scale;

    const int quad = lane >> 4;   // 0..3 -> k-chunk quad*8
    const int r16  = lane & 15;

    // A fragment base: row = wave*128 + i*16 + r16, k = kbase + s*32 + quad*8
    const ushort_t* pa = A + (size_t)(wave * 128 + r16) * K + kbase + quad * 8;
    // U fragment bases: W row n0+r16 (bv0) and n0+16+r16 (bv1), same k
    const float4* pu0 = U4 + (size_t)(n0 + r16) * K + kbase + quad * 8;
    const float4* pu1 = pu0 + (size_t)16 * K;

    f32x4 acc[8][2] = {};
    const int nsteps = kseg / BK;                      // 16

    // prologue: U fragments for step 0
    float4 ua[8], ub[8];
#pragma unroll
    for (int c = 0; c < 8; ++c) ua[c] = pu0[c];
#pragma unroll
    for (int c = 0; c < 8; ++c) ub[c] = pu1[c];

#pragma unroll 1
    for (int s = 0; s < nsteps; ++s) {
        const size_t koff = (size_t)(s + 1 < nsteps ? s + 1 : s) * BK;  // clamp last
        const ushort_t* pas = pa + (size_t)s * BK;

        // issue A fragments early (L2-resident, ~200cy, covered by dequant)
        bf16x8 av[8];
#pragma unroll
        for (int i = 0; i < 8; ++i)
            av[i] = *(const bf16x8*)(pas + (size_t)i * 16 * K);

        // issue next-step U loads; their wait lands next iteration
        float4 na[8];
#pragma unroll
        for (int c = 0; c < 8; ++c) na[c] = pu0[koff + c];

        // dequant current bv0 (regs loaded one iteration ago -> no stall)
        bf16x8 bv0;
#pragma unroll
        for (int c = 0; c < 8; ++c)
            bv0[c] = (short)f2bf(ua[c].x * t0 + ua[c].y * t1 +
                                 ua[c].z * t2 + ua[c].w * t3);

        float4 nb[8];
#pragma unroll
        for (int c = 0; c < 8; ++c) nb[c] = pu1[koff + c];

        bf16x8 bv1;
#pragma unroll
        for (int c = 0; c < 8; ++c)
            bv1[c] = (short)f2bf(ub[c].x * t0 + ub[c].y * t1 +
                                 ub[c].z * t2 + ub[c].w * t3);

#pragma unroll
        for (int i = 0; i < 8; ++i) {
            acc[i][0] = __builtin_amdgcn_mfma_f32_16x16x32_bf16(av[i], bv0, acc[i][0], 0, 0, 0);
            acc[i][1] = __builtin_amdgcn_mfma_f32_16x16x32_bf16(av[i], bv1, acc[i][1], 0, 0, 0);
        }

#pragma unroll
        for (int c = 0; c < 8; ++c) { ua[c] = na[c]; ub[c] = nb[c]; }
    }

    // epilogue: C/D layout col=lane&15, row=quad*4+reg  [verified m89/m91]
    float* outp = part + (size_t)blockIdx.y * M * N;
#pragma unroll
    for (int i = 0; i < 8; ++i) {
        const int mrow = wave * 128 + i * 16 + quad * 4;
#pragma unroll
        for (int j = 0; j < 2; ++j) {
            const int ncol = n0 + j * 16 + r16;
            float* o = outp + (size_t)mrow * N + ncol;
#pragma unroll
            for (int r = 0; r < 4; ++r)
                o[(size_t)r * N] = acc[i][j][r];
        }
    }
}

// ---------- kernel 3: out = sum_k part[k] + bias ----------
__global__ __launch_bounds__(256) void reduce_bias(const float4* __restrict__ part,
                                                   const float4* __restrict__ bias,
                                                   float4* __restrict__ out) {
    const int MN4 = (B_DIM * OUT_DIM) / 4;   // 524288
    int i = blockIdx.x * 256 + threadIdx.x;
    float4 bb = bias[i & 1023];              // OUT/4 = 1024
    float sx = bb.x, sy = bb.y, sz = bb.z, sw = bb.w;
#pragma unroll
    for (int k = 0; k < KSPLIT; ++k) {
        float4 p = part[i + (size_t)k * MN4];
        sx += p.x; sy += p.y; sz += p.z; sw += p.w;
    }
    float4 o; o.x = sx; o.y = sy; o.z = sz; o.w = sw;
    out[i] = o;
}

extern "C" void kernel_launch(void* const* d_in, const int* in_sizes, int n_in,
                              void* d_out, int out_size, void* d_ws, size_t ws_size,
                              hipStream_t stream) {
    const float* x    = (const float*)d_in[0];   // (512, 4096)
    const float* U    = (const float*)d_in[1];   // (4096*4096, 4)
    const float* q    = (const float*)d_in[2];   // (4,)
    const float* b    = (const float*)d_in[3];   // (4096,)
    const int*   expo = (const int*)d_in[4];     // scalar 0
    float* out = (float*)d_out;

    char* ws = (char*)d_ws;
    ushort_t* Xb  = (ushort_t*)ws;               // 4 MB bf16 (B, IN)
    float*    prt = (float*)(ws + 4194304);      // 64 MB fp32 partials

    // x conversion: 2.09M elems / 4 = 524288 threads
    conv_x<<<2048, 256, 0, stream>>>((const float4*)x, Xb);
    // barrier-free fused dequant-GEMM: grid (N/BN=128, KSPLIT=8) = 1024 blocks
    gemm_direct<<<dim3(128, KSPLIT), 256, 0, stream>>>(Xb, (const float4*)U, q, expo, prt);
    // reduce: 2.09M elems / 4 = 524288 threads
    reduce_bias<<<2048, 256, 0, stream>>>((const float4*)prt, (const float4*)b,
                                          (float4*)out);
}

// Round 5
// 447.755 us; speedup vs baseline: 1.4786x; 1.4786x over previous
//
#include <hip/hip_runtime.h>

typedef unsigned short ushort_t;
typedef unsigned int uint_t;
typedef __attribute__((ext_vector_type(4))) float f32x4;
typedef __attribute__((ext_vector_type(8))) short bf16x8;

#define B_DIM 512
#define IN_DIM 4096
#define OUT_DIM 4096
#define BM 128
#define BN 128
#define BK 32
#define KSPLIT 4

// ---------- helpers ----------
__device__ __forceinline__ ushort_t f2bf(float f) {
    union { float f; uint_t u; } v; v.f = f;
    uint_t r = v.u + 0x7fffu + ((v.u >> 16) & 1u);   // round-to-nearest-even
    return (ushort_t)(r >> 16);
}

// ---------- kernel 1: x -> bf16 ----------
__global__ __launch_bounds__(256) void conv_x(const float4* __restrict__ X4,
                                              ushort_t* __restrict__ Xb) {
    size_t i = (size_t)blockIdx.x * 256 + threadIdx.x;   // one float4 per thread
    float4 a = X4[i];
    ushort_t r[4] = { f2bf(a.x), f2bf(a.y), f2bf(a.z), f2bf(a.w) };
    *(uint2*)(Xb + i * 4) = *(const uint2*)r;            // 8B/lane coalesced
}

// ---------- kernel 2: fused dequant-GEMM, wave-private LDS, barrier-free ----
// R2: U latency exposed (no prefetch). R3: prefetch killed by the vmcnt(0)
// drain __syncthreads emits. R4: direct fragment loads -> 64 quarter-line
// txns/instr, L2-request-rate bound at 638 GB/s.
// Fix: wave owns a DISJOINT 128M x 32N strip, so its 32x32 W-tile staging is
// wave-private: coalesced U loads (2 rows x 512B runs/instr = 16 full lines)
// -> regs -> dequant -> ds_write -> s_waitcnt lgkmcnt(0) (intra-wave, NO
// s_barrier anywhere) -> ds_read_b128 fragments. With no barrier there is no
// vmcnt drain, so the 1-step-ahead U register prefetch truly pipelines.
// A fragments direct-from-global (R4's A pattern: 16x64B runs/instr,
// harness-verified, L2-resident, shared by all 4 waves -> L1 hits).
__global__ __launch_bounds__(256, 2) void gemm_fused_wp(
    const ushort_t* __restrict__ A,   // M x K bf16 (Xb)
    const float4* __restrict__ U4,    // (OUT*IN) float4 rows (p=0..3)
    const float* __restrict__ q,
    const int* __restrict__ expo,
    float* __restrict__ part)         // KSPLIT x M x N fp32
{
    const int M = B_DIM, N = OUT_DIM, K = IN_DIM;
    // 4 waves x 2 buffers x 1024 shorts (32x32 bf16 tile) = 16 KB
    __shared__ ushort_t sW[4 * 2 * 1024];

    const int tid  = threadIdx.x;
    const int lane = tid & 63;
    const int wave = tid >> 6;
    const int quad = lane >> 4;     // 0..3 -> k-chunk quad*8
    const int r16  = lane & 15;
    const int hi   = lane >> 5;     // 0/1: row parity within a U-load instr
    const int klo  = lane & 31;     // k position within the 32-wide step

    const int n0 = blockIdx.x * BN;
    const int m0 = blockIdx.y * BM;
    const int kseg = K / KSPLIT;                       // 1024
    const size_t kbase = (size_t)blockIdx.z * kseg;
    const int nsteps = kseg / BK;                      // 32

    const float scale = exp2f((float)expo[0]) * (1.0f / 7.0f);
    const float t0 = q[0] * scale, t1 = q[1] * scale,
                t2 = q[2] * scale, t3 = q[3] * scale;

    // A fragment base: row = m0 + i*16 + r16, k = kbase + s*32 + quad*8
    const ushort_t* pa = A + (size_t)(m0 + r16) * K + kbase + quad * 8;
    // U lane base: W row = n0 + wave*32 + 2j + hi, k element = klo
    const float4* pu = U4 + (size_t)(n0 + wave * 32 + hi) * K + kbase + klo;
    ushort_t* sWp = sW + wave * 2048;    // this wave's two 2KB buffers

    f32x4 acc[8][2] = {};

    // prologue: U tile for step 0 (16 coalesced float4 loads)
    float4 u[16];
#pragma unroll
    for (int j = 0; j < 16; ++j) u[j] = pu[(size_t)(2 * j) * K];

#pragma unroll 1
    for (int s = 0; s < nsteps; ++s) {
        ushort_t* lw = sWp + (s & 1) * 1024;

        // dequant current U regs (loaded one iteration ago -> latency hidden)
        ushort_t wv[16];
#pragma unroll
        for (int j = 0; j < 16; ++j)
            wv[j] = f2bf(u[j].x * t0 + u[j].y * t1 + u[j].z * t2 + u[j].w * t3);

        // issue next-step U loads now; their wait lands next iteration's dequant
        const size_t koff = (size_t)((s + 1 < nsteps) ? (s + 1) : s) * BK;
#pragma unroll
        for (int j = 0; j < 16; ++j) u[j] = pu[(size_t)(2 * j) * K + koff];

        // stage tile: lane writes W[2j+hi][klo]; rows 2j/2j+1 hit
        // complementary bank halves -> 2-way (free)
#pragma unroll
        for (int j = 0; j < 16; ++j)
            lw[(2 * j + hi) * 32 + klo] = wv[j];

        // A fragments, direct (16 x 64B full-line runs per instr)
        bf16x8 av[8];
#pragma unroll
        for (int i = 0; i < 8; ++i)
            av[i] = *(const bf16x8*)(pa + (size_t)(i * 16) * K + s * BK);

        // intra-wave RAW fence for the staged tile (no s_barrier: wave-private)
        asm volatile("s_waitcnt lgkmcnt(0)" ::: "memory");
        __builtin_amdgcn_sched_barrier(0);

        bf16x8 bv0 = *(const bf16x8*)(lw + r16 * 32 + quad * 8);
        bf16x8 bv1 = *(const bf16x8*)(lw + (16 + r16) * 32 + quad * 8);

#pragma unroll
        for (int i = 0; i < 8; ++i) {
            acc[i][0] = __builtin_amdgcn_mfma_f32_16x16x32_bf16(av[i], bv0, acc[i][0], 0, 0, 0);
            acc[i][1] = __builtin_amdgcn_mfma_f32_16x16x32_bf16(av[i], bv1, acc[i][1], 0, 0, 0);
        }
    }

    // epilogue: C/D layout col=lane&15, row=quad*4+reg  [verified m89/m91]
    float* outp = part + (size_t)blockIdx.z * M * N;
#pragma unroll
    for (int i = 0; i < 8; ++i) {
        const int mrow = m0 + i * 16 + quad * 4;
#pragma unroll
        for (int j = 0; j < 2; ++j) {
            const int ncol = n0 + wave * 32 + j * 16 + r16;
            float* o = outp + (size_t)mrow * N + ncol;
#pragma unroll
            for (int r = 0; r < 4; ++r)
                o[(size_t)r * N] = acc[i][j][r];
        }
    }
}

// ---------- kernel 3: out = sum_k part[k] + bias ----------
__global__ __launch_bounds__(256) void reduce_bias(const float4* __restrict__ part,
                                                   const float4* __restrict__ bias,
                                                   float4* __restrict__ out) {
    const int MN4 = (B_DIM * OUT_DIM) / 4;   // 524288
    int i = blockIdx.x * 256 + threadIdx.x;
    float4 bb = bias[i & 1023];              // OUT/4 = 1024
    float sx = bb.x, sy = bb.y, sz = bb.z, sw = bb.w;
#pragma unroll
    for (int k = 0; k < KSPLIT; ++k) {
        float4 p = part[i + (size_t)k * MN4];
        sx += p.x; sy += p.y; sz += p.z; sw += p.w;
    }
    float4 o; o.x = sx; o.y = sy; o.z = sz; o.w = sw;
    out[i] = o;
}

extern "C" void kernel_launch(void* const* d_in, const int* in_sizes, int n_in,
                              void* d_out, int out_size, void* d_ws, size_t ws_size,
                              hipStream_t stream) {
    const float* x    = (const float*)d_in[0];   // (512, 4096)
    const float* U    = (const float*)d_in[1];   // (4096*4096, 4)
    const float* q    = (const float*)d_in[2];   // (4,)
    const float* b    = (const float*)d_in[3];   // (4096,)
    const int*   expo = (const int*)d_in[4];     // scalar 0
    float* out = (float*)d_out;

    char* ws = (char*)d_ws;
    ushort_t* Xb  = (ushort_t*)ws;               // 4 MB bf16 (B, IN)
    float*    prt = (float*)(ws + 4194304);      // 32 MB fp32 partials (KSPLIT=4)

    // x conversion: 2.09M elems / 4 = 524288 threads
    conv_x<<<2048, 256, 0, stream>>>((const float4*)x, Xb);
    // fused dequant-GEMM: grid (N/BN=32, M/BM=4, KSPLIT=4) = 512 blocks
    gemm_fused_wp<<<dim3(32, 4, KSPLIT), 256, 0, stream>>>(Xb, (const float4*)U,
                                                           q, expo, prt);
    // reduce: 2.09M elems / 4 = 524288 threads
    reduce_bias<<<2048, 256, 0, stream>>>((const float4*)prt, (const float4*)b,
                                          (float4*)out);
}

// Round 6
// 419.335 us; speedup vs baseline: 1.5788x; 1.0678x over previous
//
#include <hip/hip_runtime.h>

typedef unsigned short ushort_t;
typedef unsigned int uint_t;
typedef __attribute__((ext_vector_type(4))) float f32x4;
typedef __attribute__((ext_vector_type(8))) short bf16x8;

#define B_DIM 512
#define IN_DIM 4096
#define OUT_DIM 4096
#define BN 32
#define BK 32
#define KSPLIT 4

// ---------- helpers ----------
__device__ __forceinline__ ushort_t f2bf(float f) {
    union { float f; uint_t u; } v; v.f = f;
    uint_t r = v.u + 0x7fffu + ((v.u >> 16) & 1u);   // round-to-nearest-even
    return (ushort_t)(r >> 16);
}

// ---------- kernel 1: x -> bf16 ----------
__global__ __launch_bounds__(256) void conv_x(const float4* __restrict__ X4,
                                              ushort_t* __restrict__ Xb) {
    size_t i = (size_t)blockIdx.x * 256 + threadIdx.x;   // one float4 per thread
    float4 a = X4[i];
    ushort_t r[4] = { f2bf(a.x), f2bf(a.y), f2bf(a.z), f2bf(a.w) };
    *(uint2*)(Xb + i * 4) = *(const uint2*)r;            // 8B/lane coalesced
}

// ---------- kernel 2: fused dequant-GEMM, U read ONCE, raw-barrier pipeline --
// History: R2/R3 (this tiling + __syncthreads) died on the vmcnt(0) drain the
// compiler emits before s_barrier for __syncthreads -- U prefetch cannot
// survive it. R5 (barrier-free wave-private tiles) fixed latency but BM=128
// re-read U once per M-block: 4x1.07GB redundant traffic -> 169us BW-bound.
// This version: R1 tiling (block = full M=512 x 32N, U element fetched
// exactly once per launch) + T3/T4 mechanism: raw __builtin_amdgcn_s_barrier
// does NOT drain vmcnt, so the 1-step-ahead register U prefetch stays in
// flight across the barrier; the compiler's dependence-based waitcnt at the
// dequant waits only for the older 4 loads. Double-buffered 2KB W tile,
// one barrier per step (race-free: reads of buf[s&1] complete before that
// wave's barrier(s+1); buf[s&1] rewritten only after barrier(s+1)).
// A fragments direct-from-global (R4-verified mapping; Xb is L2-resident,
// 16x64B lines/instr, ~570cy/CU/step at 56B/cy L2 rate -- not limiting).
__global__ __launch_bounds__(256, 2) void gemm_pipe(
    const ushort_t* __restrict__ A,   // M x K bf16 (Xb)
    const float4* __restrict__ U4,    // (OUT*IN) float4 rows (p=0..3)
    const float* __restrict__ q,
    const int* __restrict__ expo,
    float* __restrict__ part)         // KSPLIT x M x N fp32
{
    const int M = B_DIM, N = OUT_DIM, K = IN_DIM;
    __shared__ ushort_t sW[2 * BN * BK];   // 2 x 2KB double buffer

    const int tid  = threadIdx.x;
    const int lane = tid & 63;
    const int wave = tid >> 6;
    const int quad = lane >> 4;     // 0..3 -> k-chunk quad*8
    const int r16  = lane & 15;

    const int n0 = blockIdx.x * BN;
    const int kseg = K / KSPLIT;                       // 1024
    const size_t kbase = (size_t)blockIdx.y * kseg;
    const int nsteps = kseg / BK;                      // 32

    const float scale = exp2f((float)expo[0]) * (1.0f / 7.0f);
    const float t0 = q[0] * scale, t1 = q[1] * scale,
                t2 = q[2] * scale, t3 = q[3] * scale;

    // U staging: thread t -> W row (t>>3), k-chunk (t&7)*4 (4 float4 = 64B;
    // 8 threads cover a 512B row-run -> fully coalesced)
    const float4* gU = U4 + (size_t)(n0 + (tid >> 3)) * K + kbase + (tid & 7) * 4;
    ushort_t* lWb = sW + (tid >> 3) * BK + (tid & 7) * 4;

    // A fragment base (R4-verified): row = wave*128 + i*16 + r16, k = s*32 + quad*8
    const ushort_t* pa = A + (size_t)(wave * 128 + r16) * K + kbase + quad * 8;
    // W fragment base (R1/R2-verified): row r16 (bv0) / 16+r16 (bv1), k quad*8
    const ushort_t* fb = sW + r16 * BK + quad * 8;

    f32x4 acc[8][2] = {};

    // prologue: U regs for step 0
    float4 uc[4];
#pragma unroll
    for (int c = 0; c < 4; ++c) uc[c] = gU[c];

#pragma unroll 1
    for (int s = 0; s < nsteps; ++s) {
        // A fragments for this step (L2, ~200cy; consumed after the barrier)
        bf16x8 av[8];
#pragma unroll
        for (int i = 0; i < 8; ++i)
            av[i] = *(const bf16x8*)(pa + (size_t)i * 16 * K + (size_t)s * BK);

        // issue next-step U loads; consumed next iteration (clamped on last)
        const size_t koff = (size_t)((s + 1 < nsteps) ? (s + 1) : s) * BK;
        float4 un[4];
#pragma unroll
        for (int c = 0; c < 4; ++c) un[c] = gU[koff + c];

        // dequant step-s U (regs issued one iteration ago; compiler's
        // dependence waitcnt leaves the 12 newer loads in flight)
        ushort_t wv[4];
#pragma unroll
        for (int c = 0; c < 4; ++c)
            wv[c] = f2bf(uc[c].x * t0 + uc[c].y * t1 + uc[c].z * t2 + uc[c].w * t3);
        *(uint2*)(lWb + (s & 1) * (BN * BK)) = *(const uint2*)wv;   // 8B store

        // cross-wave visibility WITHOUT a vmcnt drain: lgkm-only wait + raw barrier
        asm volatile("s_waitcnt lgkmcnt(0)" ::: "memory");
        __builtin_amdgcn_s_barrier();

        const ushort_t* fbs = fb + (s & 1) * (BN * BK);
        bf16x8 bv0 = *(const bf16x8*)(fbs);
        bf16x8 bv1 = *(const bf16x8*)(fbs + 16 * BK);

#pragma unroll
        for (int i = 0; i < 8; ++i) {
            acc[i][0] = __builtin_amdgcn_mfma_f32_16x16x32_bf16(av[i], bv0, acc[i][0], 0, 0, 0);
            acc[i][1] = __builtin_amdgcn_mfma_f32_16x16x32_bf16(av[i], bv1, acc[i][1], 0, 0, 0);
        }

#pragma unroll
        for (int c = 0; c < 4; ++c) uc[c] = un[c];
    }

    // epilogue: C/D layout col=lane&15, row=quad*4+reg  [verified m89/m91]
    float* outp = part + (size_t)blockIdx.y * M * N;
#pragma unroll
    for (int i = 0; i < 8; ++i) {
        const int mrow = wave * 128 + i * 16 + quad * 4;
#pragma unroll
        for (int j = 0; j < 2; ++j) {
            const int ncol = n0 + j * 16 + r16;
            float* o = outp + (size_t)mrow * N + ncol;
#pragma unroll
            for (int r = 0; r < 4; ++r)
                o[(size_t)r * N] = acc[i][j][r];
        }
    }
}

// ---------- kernel 3: out = sum_k part[k] + bias ----------
__global__ __launch_bounds__(256) void reduce_bias(const float4* __restrict__ part,
                                                   const float4* __restrict__ bias,
                                                   float4* __restrict__ out) {
    const int MN4 = (B_DIM * OUT_DIM) / 4;   // 524288
    int i = blockIdx.x * 256 + threadIdx.x;
    float4 bb = bias[i & 1023];              // OUT/4 = 1024
    float sx = bb.x, sy = bb.y, sz = bb.z, sw = bb.w;
#pragma unroll
    for (int k = 0; k < KSPLIT; ++k) {
        float4 p = part[i + (size_t)k * MN4];
        sx += p.x; sy += p.y; sz += p.z; sw += p.w;
    }
    float4 o; o.x = sx; o.y = sy; o.z = sz; o.w = sw;
    out[i] = o;
}

extern "C" void kernel_launch(void* const* d_in, const int* in_sizes, int n_in,
                              void* d_out, int out_size, void* d_ws, size_t ws_size,
                              hipStream_t stream) {
    const float* x    = (const float*)d_in[0];   // (512, 4096)
    const float* U    = (const float*)d_in[1];   // (4096*4096, 4)
    const float* q    = (const float*)d_in[2];   // (4,)
    const float* b    = (const float*)d_in[3];   // (4096,)
    const int*   expo = (const int*)d_in[4];     // scalar 0
    float* out = (float*)d_out;

    char* ws = (char*)d_ws;
    ushort_t* Xb  = (ushort_t*)ws;               // 4 MB bf16 (B, IN)
    float*    prt = (float*)(ws + 4194304);      // 32 MB fp32 partials (KSPLIT=4)

    // x conversion: 2.09M elems / 4 = 524288 threads
    conv_x<<<2048, 256, 0, stream>>>((const float4*)x, Xb);
    // fused dequant-GEMM: grid (N/BN=128, KSPLIT=4) = 512 blocks, U read once
    gemm_pipe<<<dim3(128, KSPLIT), 256, 0, stream>>>(Xb, (const float4*)U,
                                                     q, expo, prt);
    // reduce: 2.09M elems / 4 = 524288 threads
    reduce_bias<<<2048, 256, 0, stream>>>((const float4*)prt, (const float4*)b,
                                          (float4*)out);
}

// Round 7
// 414.842 us; speedup vs baseline: 1.5959x; 1.0108x over previous
//
#include <hip/hip_runtime.h>

typedef unsigned short ushort_t;
typedef unsigned int uint_t;
typedef __attribute__((ext_vector_type(4))) float f32x4;
typedef __attribute__((ext_vector_type(8))) short bf16x8;

#define B_DIM 512
#define IN_DIM 4096
#define OUT_DIM 4096
#define BN 32
#define BKS 128     // k-columns staged per barrier ("stage")
#define KSPLIT 4
#define NSTAGE 8    // kseg(1024)/BKS

// ---------- helpers ----------
__device__ __forceinline__ ushort_t f2bf(float f) {
    union { float f; uint_t u; } v; v.f = f;
    uint_t r = v.u + 0x7fffu + ((v.u >> 16) & 1u);   // round-to-nearest-even
    return (ushort_t)(r >> 16);
}

// ---------- kernel 1: x -> bf16 ----------
__global__ __launch_bounds__(256) void conv_x(const float4* __restrict__ X4,
                                              ushort_t* __restrict__ Xb) {
    size_t i = (size_t)blockIdx.x * 256 + threadIdx.x;   // one float4 per thread
    float4 a = X4[i];
    ushort_t r[4] = { f2bf(a.x), f2bf(a.y), f2bf(a.z), f2bf(a.w) };
    *(uint2*)(Xb + i * 4) = *(const uint2*)r;            // 8B/lane coalesced
}

// ---------- kernel 2: fused dequant-GEMM, U once, deep stages, 8 waves ------
// R6 post-mortem: all barrier-coupled fused variants ran ~142us = 3.2x the
// 44us U-floor. Suspects: (a) 512B-run strided U streams (16k concurrent ->
// DRAM row thrash; build_w's sequential sweep gets 6.7TB/s), (b) thin
// outstanding-load cover + per-32k-step barrier lockstep. This version:
//  - BKS=128: per-row runs 2KB, barriers/segment 32->8.
//  - 512-thr blocks (8 waves, wave=64Mx32N, acc[4][2]): grid 512 = 2 blk/CU
//    = 4 waves/SIMD; U outstanding 128KB/CU >> 18KB Little's-law need.
//  - single-register-set U prefetch: dequant(uc) frees uc, reload uc for s+1
//    BEFORE the raw barrier (issue-early); its wait lands next stage.
//  - raw s_barrier (no vmcnt drain, R6-verified race-free w/ LDS dbuf).
//  - XOR-swizzled W tile (byte ^= (row&7)<<4 write+read): b128 reads at
//    256B row stride hit the bank floor instead of 2x over it.
__global__ __launch_bounds__(512, 4) void gemm_k(
    const ushort_t* __restrict__ A,   // M x K bf16 (Xb)
    const float4* __restrict__ U4,    // (OUT*IN) float4 rows (p=0..3)
    const float* __restrict__ q,
    const int* __restrict__ expo,
    float* __restrict__ part)         // KSPLIT x M x N fp32
{
    const int M = B_DIM, N = OUT_DIM, K = IN_DIM;
    __shared__ ushort_t sW[2 * BN * BKS];   // 2 x 8KB double buffer

    const int tid  = threadIdx.x;
    const int lane = tid & 63;
    const int wave = tid >> 6;      // 0..7 -> M rows [wave*64, +64)
    const int quad = lane >> 4;     // 0..3
    const int r16  = lane & 15;

    const int n0 = blockIdx.x * BN;
    const int kseg = K / KSPLIT;                       // 1024
    const size_t kbase = (size_t)blockIdx.y * kseg;

    const float scale = exp2f((float)expo[0]) * (1.0f / 7.0f);
    const float t0 = q[0] * scale, t1 = q[1] * scale,
                t2 = q[2] * scale, t3 = q[3] * scale;

    // U staging map: thread t -> W row (t>>4), k-chunk (t&15)*8 (8 float4 =
    // 128B contiguous/thread; 16 thr/row -> 2KB burst per row per stage)
    const int srow = tid >> 4;
    const int scol = (tid & 15) * 8;
    const float4* gU = U4 + (size_t)(n0 + srow) * K + kbase + scol;
    // swizzled LDS write offset (bytes within tile): row*256 + (col*16 ^ swz)
    const int wboff = srow * 256 + ((scol * 2) ^ ((srow & 7) << 4));

    // A fragment base (R4/R6-verified): row = wave*64 + i*16 + r16
    const ushort_t* pa = A + (size_t)(wave * 64 + r16) * K + kbase + quad * 8;

    // W fragment read offsets (bytes): row=(j*16+r16), col kk*32+quad*8 bf16
    const int rswz = (r16 & 7) << 4;
    const int rb0 = r16 * 256;            // j=0 row base
    const int rb1 = (16 + r16) * 256;     // j=1 row base

    f32x4 acc[4][2] = {};

    // prologue: U regs for stage 0 (8 float4 = 32 VGPR)
    float4 uc[8];
#pragma unroll
    for (int c = 0; c < 8; ++c) uc[c] = gU[c];

#pragma unroll 1
    for (int s = 0; s < NSTAGE; ++s) {
        char* buf = (char*)sW + (s & 1) * (BN * BKS * 2);

        // dequant stage-s U (loaded one stage ago; counted vmcnt leaves the
        // newer prefetch in flight), pack to bf16x8, one swizzled 16B write
        ushort_t wv[8];
#pragma unroll
        for (int c = 0; c < 8; ++c)
            wv[c] = f2bf(uc[c].x * t0 + uc[c].y * t1 + uc[c].z * t2 + uc[c].w * t3);
        *(bf16x8*)(buf + wboff) = *(const bf16x8*)wv;

        // issue stage-s+1 U loads into the SAME regs (uc dead after dequant);
        // their wait lands in next stage's dequant. Clamp on last stage.
        const float4* gUn = (s + 1 < NSTAGE) ? (gU + BKS) : gU;
#pragma unroll
        for (int c = 0; c < 8; ++c) uc[c] = gUn[c];
        gU = gUn;

        // writes visible without a vmcnt drain: lgkm-only wait + raw barrier
        asm volatile("s_waitcnt lgkmcnt(0)" ::: "memory");
        __builtin_amdgcn_s_barrier();

        // inner: 4 k-steps over the 128-wide stage tile
#pragma unroll
        for (int kk = 0; kk < 4; ++kk) {
            const int cswz = (kk * 64 + quad * 16) ^ rswz;
            bf16x8 bv0 = *(const bf16x8*)(buf + rb0 + cswz);
            bf16x8 bv1 = *(const bf16x8*)(buf + rb1 + cswz);

            bf16x8 av[4];
            const ushort_t* pak = pa + (size_t)s * BKS + kk * 32;
#pragma unroll
            for (int i = 0; i < 4; ++i)
                av[i] = *(const bf16x8*)(pak + (size_t)i * 16 * K);

#pragma unroll
            for (int i = 0; i < 4; ++i) {
                acc[i][0] = __builtin_amdgcn_mfma_f32_16x16x32_bf16(av[i], bv0, acc[i][0], 0, 0, 0);
                acc[i][1] = __builtin_amdgcn_mfma_f32_16x16x32_bf16(av[i], bv1, acc[i][1], 0, 0, 0);
            }
        }
        // one barrier per stage: next stage writes the OTHER buffer, and its
        // barrier gates reads -- race-free (R6-verified structure)
    }

    // epilogue: C/D layout col=lane&15, row=quad*4+reg  [verified m89/m91]
    float* outp = part + (size_t)blockIdx.y * M * N;
#pragma unroll
    for (int i = 0; i < 4; ++i) {
        const int mrow = wave * 64 + i * 16 + quad * 4;
#pragma unroll
        for (int j = 0; j < 2; ++j) {
            const int ncol = n0 + j * 16 + r16;
            float* o = outp + (size_t)mrow * N + ncol;
#pragma unroll
            for (int r = 0; r < 4; ++r)
                o[(size_t)r * N] = acc[i][j][r];
        }
    }
}

// ---------- kernel 3: out = sum_k part[k] + bias ----------
__global__ __launch_bounds__(256) void reduce_bias(const float4* __restrict__ part,
                                                   const float4* __restrict__ bias,
                                                   float4* __restrict__ out) {
    const int MN4 = (B_DIM * OUT_DIM) / 4;   // 524288
    int i = blockIdx.x * 256 + threadIdx.x;
    float4 bb = bias[i & 1023];              // OUT/4 = 1024
    float sx = bb.x, sy = bb.y, sz = bb.z, sw = bb.w;
#pragma unroll
    for (int k = 0; k < KSPLIT; ++k) {
        float4 p = part[i + (size_t)k * MN4];
        sx += p.x; sy += p.y; sz += p.z; sw += p.w;
    }
    float4 o; o.x = sx; o.y = sy; o.z = sz; o.w = sw;
    out[i] = o;
}

extern "C" void kernel_launch(void* const* d_in, const int* in_sizes, int n_in,
                              void* d_out, int out_size, void* d_ws, size_t ws_size,
                              hipStream_t stream) {
    const float* x    = (const float*)d_in[0];   // (512, 4096)
    const float* U    = (const float*)d_in[1];   // (4096*4096, 4)
    const float* q    = (const float*)d_in[2];   // (4,)
    const float* b    = (const float*)d_in[3];   // (4096,)
    const int*   expo = (const int*)d_in[4];     // scalar 0
    float* out = (float*)d_out;

    char* ws = (char*)d_ws;
    ushort_t* Xb  = (ushort_t*)ws;               // 4 MB bf16 (B, IN)
    float*    prt = (float*)(ws + 4194304);      // 32 MB fp32 partials (KSPLIT=4)

    // x conversion: 2.09M elems / 4 = 524288 threads
    conv_x<<<2048, 256, 0, stream>>>((const float4*)x, Xb);
    // fused dequant-GEMM: grid (N/BN=128, KSPLIT=4) = 512 blocks x 512 thr
    gemm_k<<<dim3(128, KSPLIT), 512, 0, stream>>>(Xb, (const float4*)U,
                                                  q, expo, prt);
    // reduce: 2.09M elems / 4 = 524288 threads
    reduce_bias<<<2048, 256, 0, stream>>>((const float4*)prt, (const float4*)b,
                                          (float4*)out);
}